// Round 1
// baseline (286.298 us; speedup 1.0000x reference)
//
#include <hip/hip_runtime.h>

#define N_NODES 50000
#define K_EIG   512
#define F_DIM   128
#define SPLITS  64
#define CHUNK   782   // ceil(50000/64)

typedef __attribute__((ext_vector_type(8))) short bf16x8;
typedef __attribute__((ext_vector_type(4))) float f32x4;

static __device__ __forceinline__ short f2bf(float f) {
    union { float f; unsigned u; } v; v.f = f;
    unsigned r = v.u + 0x7fffu + ((v.u >> 16) & 1u);   // round-to-nearest-even
    return (short)(r >> 16);
}

// Kernel 1: specT[f][k] += g[k] * sum_n U[n][k] * x[n][f]
// Grid: (8 k-tiles of 64, 64 n-splits). Block: 256 threads = 4 waves.
// Each wave owns a 32-wide f-slice; all waves share the 64-wide k-tile.
__global__ __launch_bounds__(256) void k_spec(
    const float* __restrict__ U, const float* __restrict__ g,
    const float* __restrict__ x, float* __restrict__ specT)
{
    const int kt    = blockIdx.x;          // 0..7
    const int split = blockIdx.y;          // 0..63
    const int tid   = threadIdx.x;
    const int wid   = tid >> 6;            // 0..3
    const int lane  = tid & 63;
    const int h     = lane >> 4;           // 0..3
    const int m     = lane & 15;           // 0..15

    const int k0 = kt * 64;
    const int f0 = wid * 32;

    const int n_start = split * CHUNK;
    int n_end = n_start + CHUNK;
    if (n_end > N_NODES) n_end = N_NODES;

    f32x4 acc[4][2];
    #pragma unroll
    for (int s = 0; s < 4; ++s)
        #pragma unroll
        for (int t = 0; t < 2; ++t)
            #pragma unroll
            for (int e = 0; e < 4; ++e) acc[s][t][e] = 0.f;

    for (int nb = n_start; nb < n_end; nb += 32) {
        bf16x8 a[4];   // A[k_local][n_red]: U[n][k0+16s+m], n = nb+8h+j
        bf16x8 b[2];   // B[n_red][f_local]: x[n][f0+16t+m]
        const int nrow = nb + 8 * h;
        #pragma unroll
        for (int j = 0; j < 8; ++j) {
            int n = nrow + j;
            bool valid = (n < n_end);
            int nc = valid ? n : (n_end - 1);           // clamped, always in-bounds
            const float* Urow = U + (long)nc * K_EIG + k0 + m;
            const float* Xrow = x + (long)nc * F_DIM + f0 + m;
            #pragma unroll
            for (int s = 0; s < 4; ++s) {
                short bv = f2bf(Urow[16 * s]);
                a[s][j] = valid ? bv : (short)0;
            }
            #pragma unroll
            for (int t = 0; t < 2; ++t) {
                short bv = f2bf(Xrow[16 * t]);
                b[t][j] = valid ? bv : (short)0;
            }
        }
        #pragma unroll
        for (int s = 0; s < 4; ++s)
            #pragma unroll
            for (int t = 0; t < 2; ++t)
                acc[s][t] = __builtin_amdgcn_mfma_f32_16x16x32_bf16(
                    a[s], b[t], acc[s][t], 0, 0, 0);
    }

    // Epilogue: scale partial by g[k], atomically accumulate into specT[f][k].
    #pragma unroll
    for (int s = 0; s < 4; ++s) {
        #pragma unroll
        for (int t = 0; t < 2; ++t) {
            #pragma unroll
            for (int r = 0; r < 4; ++r) {
                int k = k0 + 16 * s + 4 * h + r;
                int f = f0 + 16 * t + m;
                atomicAdd(&specT[(long)f * K_EIG + k], acc[s][t][r] * g[k]);
            }
        }
    }
}

// Kernel 2: out[n][f] = relu(sum_k U[n][k] * specT[f][k])   (g already folded)
// Grid: 391 blocks, each 128 rows x 128 f. Block: 4 waves in 2x2, wave = 64x64.
__global__ __launch_bounds__(256) void k_out(
    const float* __restrict__ U, const float* __restrict__ specT,
    float* __restrict__ out)
{
    const int tid  = threadIdx.x;
    const int wid  = tid >> 6;
    const int lane = tid & 63;
    const int h = lane >> 4, m = lane & 15;
    const int wr = wid >> 1, wc = wid & 1;
    const int nbase = blockIdx.x * 128 + wr * 64;
    const int fbase = wc * 64;

    f32x4 acc[4][4];
    #pragma unroll
    for (int i = 0; i < 4; ++i)
        #pragma unroll
        for (int t = 0; t < 4; ++t)
            #pragma unroll
            for (int e = 0; e < 4; ++e) acc[i][t][e] = 0.f;

    for (int kb = 0; kb < K_EIG; kb += 32) {
        bf16x8 a[4];   // A[n_local][k_red]: U[nbase+16i+m][kb+8h+j] - contiguous
        bf16x8 b[4];   // B[k_red][f_local]: specT[fbase+16t+m][kb+8h+j] - contiguous
        #pragma unroll
        for (int i = 0; i < 4; ++i) {
            int n = nbase + 16 * i + m;
            bool valid = (n < N_NODES);
            int nc = valid ? n : (N_NODES - 1);
            const f32x4* p = reinterpret_cast<const f32x4*>(
                U + (long)nc * K_EIG + kb + 8 * h);
            f32x4 lo = p[0], hi = p[1];
            #pragma unroll
            for (int j = 0; j < 4; ++j) {
                short b0 = f2bf(lo[j]), b1 = f2bf(hi[j]);
                a[i][j]     = valid ? b0 : (short)0;
                a[i][j + 4] = valid ? b1 : (short)0;
            }
        }
        #pragma unroll
        for (int t = 0; t < 4; ++t) {
            const f32x4* p = reinterpret_cast<const f32x4*>(
                specT + (long)(fbase + 16 * t + m) * K_EIG + kb + 8 * h);
            f32x4 lo = p[0], hi = p[1];
            #pragma unroll
            for (int j = 0; j < 4; ++j) {
                b[t][j]     = f2bf(lo[j]);
                b[t][j + 4] = f2bf(hi[j]);
            }
        }
        #pragma unroll
        for (int i = 0; i < 4; ++i)
            #pragma unroll
            for (int t = 0; t < 4; ++t)
                acc[i][t] = __builtin_amdgcn_mfma_f32_16x16x32_bf16(
                    a[i], b[t], acc[i][t], 0, 0, 0);
    }

    #pragma unroll
    for (int i = 0; i < 4; ++i) {
        #pragma unroll
        for (int r = 0; r < 4; ++r) {
            int n = nbase + 16 * i + 4 * h + r;
            if (n < N_NODES) {
                float* orow = out + (long)n * F_DIM + fbase + m;
                #pragma unroll
                for (int t = 0; t < 4; ++t)
                    orow[16 * t] = fmaxf(acc[i][t][r], 0.f);
            }
        }
    }
}

extern "C" void kernel_launch(void* const* d_in, const int* in_sizes, int n_in,
                              void* d_out, int out_size, void* d_ws, size_t ws_size,
                              hipStream_t stream) {
    const float* U = (const float*)d_in[0];   // eigenvectors [50000,512]
    const float* g = (const float*)d_in[1];   // spectral_filters [512]
    const float* x = (const float*)d_in[2];   // x [50000,128]
    float* out   = (float*)d_out;
    float* specT = (float*)d_ws;              // [128][512] f32 = 256 KB

    hipMemsetAsync(specT, 0, (size_t)K_EIG * F_DIM * sizeof(float), stream);

    dim3 g1(K_EIG / 64, SPLITS);              // 8 x 64 = 512 blocks
    k_spec<<<g1, 256, 0, stream>>>(U, g, x, specT);

    int nblocks2 = (N_NODES + 127) / 128;     // 391
    k_out<<<nblocks2, 256, 0, stream>>>(U, specT, out);
}

// Round 2
// 191.847 us; speedup vs baseline: 1.4923x; 1.4923x over previous
//
#include <hip/hip_runtime.h>
#include <hip/hip_bf16.h>

#define N_NODES 50000
#define K_EIG   512
#define F_DIM   128
#define NPAD    51200     // padded n dim: 64 splits * 800
#define CHUNK   800
#define NSPLITS 64

typedef __attribute__((ext_vector_type(8))) short bf16x8;
typedef __attribute__((ext_vector_type(4))) float f32x4;

static __device__ __forceinline__ unsigned pk2(float lo, float hi) {
    // two f32 -> packed 2x bf16 (low addr in low half). Compiler emits cvt_pk.
    unsigned short a = __builtin_bit_cast(unsigned short, __float2bfloat16(lo));
    unsigned short b = __builtin_bit_cast(unsigned short, __float2bfloat16(hi));
    return ((unsigned)b << 16) | (unsigned)a;
}

static __device__ __forceinline__ short f2bf(float f) {
    union { float f; unsigned u; } v; v.f = f;
    unsigned r = v.u + 0x7fffu + ((v.u >> 16) & 1u);
    return (short)(r >> 16);
}

// ---------------- prep: U -> Ubf[n][k] bf16  and  UT[k][n(pad)] bf16 ----------
__global__ __launch_bounds__(256) void prep_u(const float* __restrict__ U,
                                              unsigned* __restrict__ Ubf,
                                              unsigned* __restrict__ UT)
{
    const int n0 = blockIdx.x * 64;
    const int k0 = blockIdx.y * 64;
    const int a  = threadIdx.x & 15;   // n micro-block (4 rows)
    const int b  = threadIdx.x >> 4;   // k micro-block (4 cols)
    const int n  = n0 + 4 * a;
    const int k  = k0 + 4 * b;

    float r[4][4];
    #pragma unroll
    for (int j = 0; j < 4; ++j) {
        int nr = n + j;
        if (nr < N_NODES) {
            f32x4 v = *reinterpret_cast<const f32x4*>(U + (long)nr * K_EIG + k);
            r[j][0] = v[0]; r[j][1] = v[1]; r[j][2] = v[2]; r[j][3] = v[3];
        } else {
            r[j][0] = r[j][1] = r[j][2] = r[j][3] = 0.f;
        }
    }
    #pragma unroll
    for (int j = 0; j < 4; ++j) {
        int nr = n + j;
        if (nr < N_NODES) {
            unsigned* p = Ubf + ((long)nr * K_EIG + k) / 2;
            p[0] = pk2(r[j][0], r[j][1]);
            p[1] = pk2(r[j][2], r[j][3]);
        }
    }
    #pragma unroll
    for (int i = 0; i < 4; ++i) {
        unsigned* p = UT + ((long)(k + i) * NPAD + n) / 2;
        p[0] = pk2(r[0][i], r[1][i]);
        p[1] = pk2(r[2][i], r[3][i]);
    }
}

// ---------------- prep: x -> xT[f][n(pad)] bf16 ------------------------------
__global__ __launch_bounds__(256) void prep_x(const float* __restrict__ x,
                                              unsigned* __restrict__ xT)
{
    const int n0 = blockIdx.x * 64;
    const int f0 = blockIdx.y * 64;
    const int a  = threadIdx.x & 15;
    const int b  = threadIdx.x >> 4;
    const int n  = n0 + 4 * a;
    const int f  = f0 + 4 * b;

    float r[4][4];
    #pragma unroll
    for (int j = 0; j < 4; ++j) {
        int nr = n + j;
        if (nr < N_NODES) {
            f32x4 v = *reinterpret_cast<const f32x4*>(x + (long)nr * F_DIM + f);
            r[j][0] = v[0]; r[j][1] = v[1]; r[j][2] = v[2]; r[j][3] = v[3];
        } else {
            r[j][0] = r[j][1] = r[j][2] = r[j][3] = 0.f;
        }
    }
    #pragma unroll
    for (int i = 0; i < 4; ++i) {
        unsigned* p = xT + ((long)(f + i) * NPAD + n) / 2;
        p[0] = pk2(r[0][i], r[1][i]);
        p[1] = pk2(r[2][i], r[3][i]);
    }
}

// ---------------- GEMM1: spec[f][k] += g[k] * sum_n UT[k][n]*xT[f][n] --------
// grid (8 k-tiles, 64 n-splits); 4 waves; no LDS, direct 16B bf16 loads.
__global__ __launch_bounds__(256) void k_spec(
    const unsigned short* __restrict__ UT, const unsigned short* __restrict__ xT,
    const float* __restrict__ g, float* __restrict__ spec)
{
    const int kt    = blockIdx.x;
    const int split = blockIdx.y;
    const int tid   = threadIdx.x;
    const int wid   = tid >> 6;
    const int lane  = tid & 63;
    const int h     = lane >> 4;
    const int m     = lane & 15;
    const int k0    = kt * 64;
    const int f0    = wid * 32;
    const int nbeg  = split * CHUNK;

    f32x4 acc[4][2];
    #pragma unroll
    for (int s = 0; s < 4; ++s)
        #pragma unroll
        for (int t = 0; t < 2; ++t)
            #pragma unroll
            for (int e = 0; e < 4; ++e) acc[s][t][e] = 0.f;

    const unsigned short* Abase = UT + (long)(k0 + m) * NPAD + 8 * h;
    const unsigned short* Bbase = xT + (long)(f0 + m) * NPAD + 8 * h;

    for (int nb = nbeg; nb < nbeg + CHUNK; nb += 32) {
        bf16x8 a[4], b[2];
        #pragma unroll
        for (int s = 0; s < 4; ++s)
            a[s] = *reinterpret_cast<const bf16x8*>(Abase + (long)16 * s * NPAD + nb);
        #pragma unroll
        for (int t = 0; t < 2; ++t)
            b[t] = *reinterpret_cast<const bf16x8*>(Bbase + (long)16 * t * NPAD + nb);
        #pragma unroll
        for (int s = 0; s < 4; ++s)
            #pragma unroll
            for (int t = 0; t < 2; ++t)
                acc[s][t] = __builtin_amdgcn_mfma_f32_16x16x32_bf16(
                    a[s], b[t], acc[s][t], 0, 0, 0);
    }

    #pragma unroll
    for (int s = 0; s < 4; ++s)
        #pragma unroll
        for (int t = 0; t < 2; ++t)
            #pragma unroll
            for (int r = 0; r < 4; ++r) {
                int k = k0 + 16 * s + 4 * h + r;
                int f = f0 + 16 * t + m;
                atomicAdd(&spec[(long)f * K_EIG + k], acc[s][t][r] * g[k]);
            }
}

// ---------------- spec f32 -> bf16 -------------------------------------------
__global__ __launch_bounds__(256) void k_cvt(const float* __restrict__ spec,
                                             unsigned short* __restrict__ specbf)
{
    int i = blockIdx.x * 256 + threadIdx.x;
    specbf[i] = (unsigned short)__builtin_bit_cast(
        unsigned short, __float2bfloat16(spec[i]));
}

// ---------------- GEMM2: out[n][f] = relu(sum_k Ubf[n][k]*specbf[f][k]) ------
__global__ __launch_bounds__(256) void k_out(
    const unsigned short* __restrict__ Ubf,
    const unsigned short* __restrict__ specbf,
    float* __restrict__ out)
{
    const int tid  = threadIdx.x;
    const int wid  = tid >> 6;
    const int lane = tid & 63;
    const int h = lane >> 4, m = lane & 15;
    const int wr = wid >> 1, wc = wid & 1;
    const int nbase = blockIdx.x * 128 + wr * 64;
    const int fbase = wc * 64;

    f32x4 acc[4][4];
    #pragma unroll
    for (int i = 0; i < 4; ++i)
        #pragma unroll
        for (int t = 0; t < 4; ++t)
            #pragma unroll
            for (int e = 0; e < 4; ++e) acc[i][t][e] = 0.f;

    for (int kb = 0; kb < K_EIG; kb += 32) {
        bf16x8 a[4], b[4];
        #pragma unroll
        for (int i = 0; i < 4; ++i) {
            int n = nbase + 16 * i + m;
            int nc = (n < N_NODES) ? n : (N_NODES - 1);
            a[i] = *reinterpret_cast<const bf16x8*>(
                Ubf + (long)nc * K_EIG + kb + 8 * h);
        }
        #pragma unroll
        for (int t = 0; t < 4; ++t)
            b[t] = *reinterpret_cast<const bf16x8*>(
                specbf + (long)(fbase + 16 * t + m) * K_EIG + kb + 8 * h);
        #pragma unroll
        for (int i = 0; i < 4; ++i)
            #pragma unroll
            for (int t = 0; t < 4; ++t)
                acc[i][t] = __builtin_amdgcn_mfma_f32_16x16x32_bf16(
                    a[i], b[t], acc[i][t], 0, 0, 0);
    }

    #pragma unroll
    for (int i = 0; i < 4; ++i)
        #pragma unroll
        for (int r = 0; r < 4; ++r) {
            int n = nbase + 16 * i + 4 * h + r;
            if (n < N_NODES) {
                float* orow = out + (long)n * F_DIM + fbase + m;
                #pragma unroll
                for (int t = 0; t < 4; ++t)
                    orow[16 * t] = fmaxf(acc[i][t][r], 0.f);
            }
        }
}

// =================== fallback (round-1) path if ws too small =================
__global__ __launch_bounds__(256) void k_spec_v1(
    const float* __restrict__ U, const float* __restrict__ g,
    const float* __restrict__ x, float* __restrict__ specT)
{
    const int kt    = blockIdx.x;
    const int split = blockIdx.y;
    const int tid   = threadIdx.x;
    const int wid   = tid >> 6;
    const int lane  = tid & 63;
    const int h     = lane >> 4;
    const int m     = lane & 15;
    const int k0 = kt * 64;
    const int f0 = wid * 32;
    const int chunk1 = 782;
    const int n_start = split * chunk1;
    int n_end = n_start + chunk1;
    if (n_end > N_NODES) n_end = N_NODES;

    f32x4 acc[4][2];
    #pragma unroll
    for (int s = 0; s < 4; ++s)
        #pragma unroll
        for (int t = 0; t < 2; ++t)
            #pragma unroll
            for (int e = 0; e < 4; ++e) acc[s][t][e] = 0.f;

    for (int nb = n_start; nb < n_end; nb += 32) {
        bf16x8 a[4]; bf16x8 b[2];
        const int nrow = nb + 8 * h;
        #pragma unroll
        for (int j = 0; j < 8; ++j) {
            int n = nrow + j;
            bool valid = (n < n_end);
            int nc = valid ? n : (n_end - 1);
            const float* Urow = U + (long)nc * K_EIG + k0 + m;
            const float* Xrow = x + (long)nc * F_DIM + f0 + m;
            #pragma unroll
            for (int s = 0; s < 4; ++s) {
                short bv = f2bf(Urow[16 * s]);
                a[s][j] = valid ? bv : (short)0;
            }
            #pragma unroll
            for (int t = 0; t < 2; ++t) {
                short bv = f2bf(Xrow[16 * t]);
                b[t][j] = valid ? bv : (short)0;
            }
        }
        #pragma unroll
        for (int s = 0; s < 4; ++s)
            #pragma unroll
            for (int t = 0; t < 2; ++t)
                acc[s][t] = __builtin_amdgcn_mfma_f32_16x16x32_bf16(
                    a[s], b[t], acc[s][t], 0, 0, 0);
    }
    #pragma unroll
    for (int s = 0; s < 4; ++s)
        #pragma unroll
        for (int t = 0; t < 2; ++t)
            #pragma unroll
            for (int r = 0; r < 4; ++r) {
                int k = k0 + 16 * s + 4 * h + r;
                int f = f0 + 16 * t + m;
                atomicAdd(&specT[(long)f * K_EIG + k], acc[s][t][r] * g[k]);
            }
}

__global__ __launch_bounds__(256) void k_out_v1(
    const float* __restrict__ U, const float* __restrict__ specT,
    float* __restrict__ out)
{
    const int tid  = threadIdx.x;
    const int wid  = tid >> 6;
    const int lane = tid & 63;
    const int h = lane >> 4, m = lane & 15;
    const int wr = wid >> 1, wc = wid & 1;
    const int nbase = blockIdx.x * 128 + wr * 64;
    const int fbase = wc * 64;

    f32x4 acc[4][4];
    #pragma unroll
    for (int i = 0; i < 4; ++i)
        #pragma unroll
        for (int t = 0; t < 4; ++t)
            #pragma unroll
            for (int e = 0; e < 4; ++e) acc[i][t][e] = 0.f;

    for (int kb = 0; kb < K_EIG; kb += 32) {
        bf16x8 a[4], b[4];
        #pragma unroll
        for (int i = 0; i < 4; ++i) {
            int n = nbase + 16 * i + m;
            bool valid = (n < N_NODES);
            int nc = valid ? n : (N_NODES - 1);
            const f32x4* p = reinterpret_cast<const f32x4*>(
                U + (long)nc * K_EIG + kb + 8 * h);
            f32x4 lo = p[0], hi = p[1];
            #pragma unroll
            for (int j = 0; j < 4; ++j) {
                short b0 = f2bf(lo[j]), b1 = f2bf(hi[j]);
                a[i][j]     = valid ? b0 : (short)0;
                a[i][j + 4] = valid ? b1 : (short)0;
            }
        }
        #pragma unroll
        for (int t = 0; t < 4; ++t) {
            const f32x4* p = reinterpret_cast<const f32x4*>(
                specT + (long)(fbase + 16 * t + m) * K_EIG + kb + 8 * h);
            f32x4 lo = p[0], hi = p[1];
            #pragma unroll
            for (int j = 0; j < 4; ++j) {
                b[t][j]     = f2bf(lo[j]);
                b[t][j + 4] = f2bf(hi[j]);
            }
        }
        #pragma unroll
        for (int i = 0; i < 4; ++i)
            #pragma unroll
            for (int t = 0; t < 4; ++t)
                acc[i][t] = __builtin_amdgcn_mfma_f32_16x16x32_bf16(
                    a[i], b[t], acc[i][t], 0, 0, 0);
    }
    #pragma unroll
    for (int i = 0; i < 4; ++i)
        #pragma unroll
        for (int r = 0; r < 4; ++r) {
            int n = nbase + 16 * i + 4 * h + r;
            if (n < N_NODES) {
                float* orow = out + (long)n * F_DIM + fbase + m;
                #pragma unroll
                for (int t = 0; t < 4; ++t)
                    orow[16 * t] = fmaxf(acc[i][t][r], 0.f);
            }
        }
}

// ============================================================================
extern "C" void kernel_launch(void* const* d_in, const int* in_sizes, int n_in,
                              void* d_out, int out_size, void* d_ws, size_t ws_size,
                              hipStream_t stream) {
    const float* U = (const float*)d_in[0];
    const float* g = (const float*)d_in[1];
    const float* x = (const float*)d_in[2];
    float* out = (float*)d_out;

    // ws layout (bytes)
    const size_t OFF_UT    = 0;                       // 512*51200*2   = 52,428,800
    const size_t OFF_XT    = 52428800;                // 128*51200*2   = 13,107,200
    const size_t OFF_UBF   = 65536000;                // 50000*512*2   = 51,200,000
    const size_t OFF_SPEC  = 116736000;               // 512*128*4     =    262,144
    const size_t OFF_SPECB = 116998144;               // 512*128*2     =    131,072
    const size_t WS_NEEDED = 117129216;

    if (ws_size >= WS_NEEDED) {
        unsigned*       UT     = (unsigned*)((char*)d_ws + OFF_UT);
        unsigned*       xT     = (unsigned*)((char*)d_ws + OFF_XT);
        unsigned*       Ubf    = (unsigned*)((char*)d_ws + OFF_UBF);
        float*          spec   = (float*)((char*)d_ws + OFF_SPEC);
        unsigned short* specbf = (unsigned short*)((char*)d_ws + OFF_SPECB);

        hipMemsetAsync(spec, 0, (size_t)K_EIG * F_DIM * sizeof(float), stream);

        dim3 gu(NPAD / 64, K_EIG / 64);   // 800 x 8
        prep_u<<<gu, 256, 0, stream>>>(U, Ubf, UT);

        dim3 gx(NPAD / 64, F_DIM / 64);   // 800 x 2
        prep_x<<<gx, 256, 0, stream>>>(x, xT);

        dim3 g1(K_EIG / 64, NSPLITS);     // 8 x 64
        k_spec<<<g1, 256, 0, stream>>>((const unsigned short*)UT,
                                       (const unsigned short*)xT, g, spec);

        k_cvt<<<(K_EIG * F_DIM) / 256, 256, 0, stream>>>(spec, specbf);

        int nb2 = (N_NODES + 127) / 128;  // 391
        k_out<<<nb2, 256, 0, stream>>>((const unsigned short*)Ubf, specbf, out);
    } else {
        float* specT = (float*)d_ws;      // 256 KB
        hipMemsetAsync(specT, 0, (size_t)K_EIG * F_DIM * sizeof(float), stream);
        dim3 g1(K_EIG / 64, 64);
        k_spec_v1<<<g1, 256, 0, stream>>>(U, g, x, specT);
        int nb2 = (N_NODES + 127) / 128;
        k_out_v1<<<nb2, 256, 0, stream>>>(U, specT, out);
    }
}

// Round 3
// 155.121 us; speedup vs baseline: 1.8456x; 1.2368x over previous
//
#include <hip/hip_runtime.h>
#include <hip/hip_bf16.h>

#define N_NODES 50000
#define K_EIG   512
#define F_DIM   128
#define NPAD    51200     // 200 splits * 256
#define NSPLITS 200
#define CHUNK   256

typedef __attribute__((ext_vector_type(8))) short bf16x8;
typedef __attribute__((ext_vector_type(4))) short s16x4;
typedef __attribute__((ext_vector_type(4))) float f32x4;

static __device__ __forceinline__ unsigned pk2(float lo, float hi) {
    unsigned short a = __builtin_bit_cast(unsigned short, __float2bfloat16(lo));
    unsigned short b = __builtin_bit_cast(unsigned short, __float2bfloat16(hi));
    return ((unsigned)b << 16) | (unsigned)a;
}

static __device__ __forceinline__ short f2bf(float f) {
    union { float f; unsigned u; } v; v.f = f;
    unsigned r = v.u + 0x7fffu + ((v.u >> 16) & 1u);   // RNE
    return (short)(r >> 16);
}

static __device__ __forceinline__ float bf2f(unsigned short u) {
    union { unsigned u; float f; } v; v.u = ((unsigned)u) << 16;
    return v.f;
}

// ---------------- prep: U -> UT[k][n(pad)] bf16 ------------------------------
__global__ __launch_bounds__(256) void prep_u(const float* __restrict__ U,
                                              unsigned* __restrict__ UT)
{
    const int n0 = blockIdx.x * 64;
    const int k0 = blockIdx.y * 64;
    const int a  = threadIdx.x & 15;
    const int b  = threadIdx.x >> 4;
    const int n  = n0 + 4 * a;
    const int k  = k0 + 4 * b;

    float r[4][4];
    #pragma unroll
    for (int j = 0; j < 4; ++j) {
        int nr = n + j;
        if (nr < N_NODES) {
            f32x4 v = *reinterpret_cast<const f32x4*>(U + (long)nr * K_EIG + k);
            r[j][0] = v[0]; r[j][1] = v[1]; r[j][2] = v[2]; r[j][3] = v[3];
        } else {
            r[j][0] = r[j][1] = r[j][2] = r[j][3] = 0.f;
        }
    }
    #pragma unroll
    for (int i = 0; i < 4; ++i) {
        unsigned* p = UT + ((long)(k + i) * NPAD + n) / 2;
        p[0] = pk2(r[0][i], r[1][i]);
        p[1] = pk2(r[2][i], r[3][i]);
    }
}

// ---------------- prep: x -> xT[f][n(pad)] bf16 ------------------------------
__global__ __launch_bounds__(256) void prep_x(const float* __restrict__ x,
                                              unsigned* __restrict__ xT)
{
    const int n0 = blockIdx.x * 64;
    const int f0 = blockIdx.y * 64;
    const int a  = threadIdx.x & 15;
    const int b  = threadIdx.x >> 4;
    const int n  = n0 + 4 * a;
    const int f  = f0 + 4 * b;

    float r[4][4];
    #pragma unroll
    for (int j = 0; j < 4; ++j) {
        int nr = n + j;
        if (nr < N_NODES) {
            f32x4 v = *reinterpret_cast<const f32x4*>(x + (long)nr * F_DIM + f);
            r[j][0] = v[0]; r[j][1] = v[1]; r[j][2] = v[2]; r[j][3] = v[3];
        } else {
            r[j][0] = r[j][1] = r[j][2] = r[j][3] = 0.f;
        }
    }
    #pragma unroll
    for (int i = 0; i < 4; ++i) {
        unsigned* p = xT + ((long)(f + i) * NPAD + n) / 2;
        p[0] = pk2(r[0][i], r[1][i]);
        p[1] = pk2(r[2][i], r[3][i]);
    }
}

// ---------------- GEMM1: partial[split][f][k] = sum_n UT[k][n]*xT[f][n] ------
// grid (8 k-tiles, 200 n-splits); 4 waves; no LDS, no atomics.
__global__ __launch_bounds__(256) void k_spec(
    const unsigned short* __restrict__ UT, const unsigned short* __restrict__ xT,
    unsigned short* __restrict__ partial)
{
    const int kt    = blockIdx.x;
    const int split = blockIdx.y;
    const int tid   = threadIdx.x;
    const int wid   = tid >> 6;
    const int lane  = tid & 63;
    const int h     = lane >> 4;
    const int m     = lane & 15;
    const int k0    = kt * 64;
    const int f0    = wid * 32;
    const int nbeg  = split * CHUNK;

    f32x4 acc[4][2];
    #pragma unroll
    for (int s = 0; s < 4; ++s)
        #pragma unroll
        for (int t = 0; t < 2; ++t)
            #pragma unroll
            for (int e = 0; e < 4; ++e) acc[s][t][e] = 0.f;

    const unsigned short* Abase = UT + (long)(k0 + m) * NPAD + 8 * h;
    const unsigned short* Bbase = xT + (long)(f0 + m) * NPAD + 8 * h;

    for (int nb = nbeg; nb < nbeg + CHUNK; nb += 32) {
        bf16x8 a[4], b[2];
        #pragma unroll
        for (int s = 0; s < 4; ++s)
            a[s] = *reinterpret_cast<const bf16x8*>(Abase + (long)16 * s * NPAD + nb);
        #pragma unroll
        for (int t = 0; t < 2; ++t)
            b[t] = *reinterpret_cast<const bf16x8*>(Bbase + (long)16 * t * NPAD + nb);
        #pragma unroll
        for (int s = 0; s < 4; ++s)
            #pragma unroll
            for (int t = 0; t < 2; ++t)
                acc[s][t] = __builtin_amdgcn_mfma_f32_16x16x32_bf16(
                    a[s], b[t], acc[s][t], 0, 0, 0);
    }

    // epilogue: private partial tile, bf16, 8B vector stores, no contention
    unsigned short* pbase = partial + (long)split * (F_DIM * K_EIG);
    #pragma unroll
    for (int s = 0; s < 4; ++s)
        #pragma unroll
        for (int t = 0; t < 2; ++t) {
            int k = k0 + 16 * s + 4 * h;
            int f = f0 + 16 * t + m;
            s16x4 v;
            #pragma unroll
            for (int r = 0; r < 4; ++r) v[r] = f2bf(acc[s][t][r]);
            *reinterpret_cast<s16x4*>(pbase + (long)f * K_EIG + k) = v;
        }
}

// ---------------- reduce partials, fold g, emit bf16 spec --------------------
__global__ __launch_bounds__(256) void k_reduce(
    const unsigned short* __restrict__ partial, const float* __restrict__ g,
    unsigned short* __restrict__ specbf)
{
    int idx = blockIdx.x * 256 + threadIdx.x;   // 0..65535
    float s = 0.f;
    #pragma unroll 8
    for (int p = 0; p < NSPLITS; ++p)
        s += bf2f(partial[(long)p * (F_DIM * K_EIG) + idx]);
    int k = idx & (K_EIG - 1);
    specbf[idx] = (unsigned short)f2bf(s * g[k]);
}

// ---------------- GEMM2: out[n][f] = relu(sum_k U[n][k]*specbf[f][k]) --------
// 64n x 128f tile per block, 782 blocks; A converted inline from f32 U.
__global__ __launch_bounds__(256) void k_out(
    const float* __restrict__ U, const unsigned short* __restrict__ specbf,
    float* __restrict__ out)
{
    const int tid  = threadIdx.x;
    const int wid  = tid >> 6;
    const int lane = tid & 63;
    const int h = lane >> 4, m = lane & 15;
    const int wr = wid >> 1, wc = wid & 1;
    const int nbase = blockIdx.x * 64 + wr * 32;
    const int fbase = wc * 64;

    f32x4 acc[2][4];
    #pragma unroll
    for (int i = 0; i < 2; ++i)
        #pragma unroll
        for (int t = 0; t < 4; ++t)
            #pragma unroll
            for (int e = 0; e < 4; ++e) acc[i][t][e] = 0.f;

    for (int kb = 0; kb < K_EIG; kb += 32) {
        bf16x8 a[2], b[4];
        #pragma unroll
        for (int i = 0; i < 2; ++i) {
            int n = nbase + 16 * i + m;
            int nc = (n < N_NODES) ? n : (N_NODES - 1);
            const f32x4* p = reinterpret_cast<const f32x4*>(
                U + (long)nc * K_EIG + kb + 8 * h);
            f32x4 lo = p[0], hi = p[1];
            #pragma unroll
            for (int j = 0; j < 4; ++j) {
                a[i][j]     = f2bf(lo[j]);
                a[i][j + 4] = f2bf(hi[j]);
            }
        }
        #pragma unroll
        for (int t = 0; t < 4; ++t)
            b[t] = *reinterpret_cast<const bf16x8*>(
                specbf + (long)(fbase + 16 * t + m) * K_EIG + kb + 8 * h);
        #pragma unroll
        for (int i = 0; i < 2; ++i)
            #pragma unroll
            for (int t = 0; t < 4; ++t)
                acc[i][t] = __builtin_amdgcn_mfma_f32_16x16x32_bf16(
                    a[i], b[t], acc[i][t], 0, 0, 0);
    }

    #pragma unroll
    for (int i = 0; i < 2; ++i)
        #pragma unroll
        for (int r = 0; r < 4; ++r) {
            int n = nbase + 16 * i + 4 * h + r;
            if (n < N_NODES) {
                float* orow = out + (long)n * F_DIM + fbase + m;
                #pragma unroll
                for (int t = 0; t < 4; ++t)
                    orow[16 * t] = fmaxf(acc[i][t][r], 0.f);
            }
        }
}

// =================== fallback (round-1) path if ws too small =================
__global__ __launch_bounds__(256) void k_spec_v1(
    const float* __restrict__ U, const float* __restrict__ g,
    const float* __restrict__ x, float* __restrict__ specT)
{
    const int kt    = blockIdx.x;
    const int split = blockIdx.y;
    const int tid   = threadIdx.x;
    const int wid   = tid >> 6;
    const int lane  = tid & 63;
    const int h     = lane >> 4;
    const int m     = lane & 15;
    const int k0 = kt * 64;
    const int f0 = wid * 32;
    const int chunk1 = 782;
    const int n_start = split * chunk1;
    int n_end = n_start + chunk1;
    if (n_end > N_NODES) n_end = N_NODES;

    f32x4 acc[4][2];
    #pragma unroll
    for (int s = 0; s < 4; ++s)
        #pragma unroll
        for (int t = 0; t < 2; ++t)
            #pragma unroll
            for (int e = 0; e < 4; ++e) acc[s][t][e] = 0.f;

    for (int nb = n_start; nb < n_end; nb += 32) {
        bf16x8 a[4]; bf16x8 b[2];
        const int nrow = nb + 8 * h;
        #pragma unroll
        for (int j = 0; j < 8; ++j) {
            int n = nrow + j;
            bool valid = (n < n_end);
            int nc = valid ? n : (n_end - 1);
            const float* Urow = U + (long)nc * K_EIG + k0 + m;
            const float* Xrow = x + (long)nc * F_DIM + f0 + m;
            #pragma unroll
            for (int s = 0; s < 4; ++s) {
                short bv = f2bf(Urow[16 * s]);
                a[s][j] = valid ? bv : (short)0;
            }
            #pragma unroll
            for (int t = 0; t < 2; ++t) {
                short bv = f2bf(Xrow[16 * t]);
                b[t][j] = valid ? bv : (short)0;
            }
        }
        #pragma unroll
        for (int s = 0; s < 4; ++s)
            #pragma unroll
            for (int t = 0; t < 2; ++t)
                acc[s][t] = __builtin_amdgcn_mfma_f32_16x16x32_bf16(
                    a[s], b[t], acc[s][t], 0, 0, 0);
    }
    #pragma unroll
    for (int s = 0; s < 4; ++s)
        #pragma unroll
        for (int t = 0; t < 2; ++t)
            #pragma unroll
            for (int r = 0; r < 4; ++r) {
                int k = k0 + 16 * s + 4 * h + r;
                int f = f0 + 16 * t + m;
                atomicAdd(&specT[(long)f * K_EIG + k], acc[s][t][r] * g[k]);
            }
}

__global__ __launch_bounds__(256) void k_out_v1(
    const float* __restrict__ U, const float* __restrict__ specT,
    float* __restrict__ out)
{
    const int tid  = threadIdx.x;
    const int wid  = tid >> 6;
    const int lane = tid & 63;
    const int h = lane >> 4, m = lane & 15;
    const int wr = wid >> 1, wc = wid & 1;
    const int nbase = blockIdx.x * 128 + wr * 64;
    const int fbase = wc * 64;

    f32x4 acc[4][4];
    #pragma unroll
    for (int i = 0; i < 4; ++i)
        #pragma unroll
        for (int t = 0; t < 4; ++t)
            #pragma unroll
            for (int e = 0; e < 4; ++e) acc[i][t][e] = 0.f;

    for (int kb = 0; kb < K_EIG; kb += 32) {
        bf16x8 a[4], b[4];
        #pragma unroll
        for (int i = 0; i < 4; ++i) {
            int n = nbase + 16 * i + m;
            bool valid = (n < N_NODES);
            int nc = valid ? n : (N_NODES - 1);
            const f32x4* p = reinterpret_cast<const f32x4*>(
                U + (long)nc * K_EIG + kb + 8 * h);
            f32x4 lo = p[0], hi = p[1];
            #pragma unroll
            for (int j = 0; j < 4; ++j) {
                short b0 = f2bf(lo[j]), b1 = f2bf(hi[j]);
                a[i][j]     = valid ? b0 : (short)0;
                a[i][j + 4] = valid ? b1 : (short)0;
            }
        }
        #pragma unroll
        for (int t = 0; t < 4; ++t) {
            const f32x4* p = reinterpret_cast<const f32x4*>(
                specT + (long)(fbase + 16 * t + m) * K_EIG + kb + 8 * h);
            f32x4 lo = p[0], hi = p[1];
            #pragma unroll
            for (int j = 0; j < 4; ++j) {
                b[t][j]     = f2bf(lo[j]);
                b[t][j + 4] = f2bf(hi[j]);
            }
        }
        #pragma unroll
        for (int i = 0; i < 4; ++i)
            #pragma unroll
            for (int t = 0; t < 4; ++t)
                acc[i][t] = __builtin_amdgcn_mfma_f32_16x16x32_bf16(
                    a[i], b[t], acc[i][t], 0, 0, 0);
    }
    #pragma unroll
    for (int i = 0; i < 4; ++i)
        #pragma unroll
        for (int r = 0; r < 4; ++r) {
            int n = nbase + 16 * i + 4 * h + r;
            if (n < N_NODES) {
                float* orow = out + (long)n * F_DIM + fbase + m;
                #pragma unroll
                for (int t = 0; t < 4; ++t)
                    orow[16 * t] = fmaxf(acc[i][t][r], 0.f);
            }
        }
}

// ============================================================================
extern "C" void kernel_launch(void* const* d_in, const int* in_sizes, int n_in,
                              void* d_out, int out_size, void* d_ws, size_t ws_size,
                              hipStream_t stream) {
    const float* U = (const float*)d_in[0];
    const float* g = (const float*)d_in[1];
    const float* x = (const float*)d_in[2];
    float* out = (float*)d_out;

    // ws layout (bytes)
    const size_t OFF_UT    = 0;                 // 512*51200*2       = 52,428,800
    const size_t OFF_XT    = 52428800;          // 128*51200*2       = 13,107,200
    const size_t OFF_PART  = 65536000;          // 200*128*512*2     = 26,214,400
    const size_t OFF_SPECB = 91750400;          // 128*512*2         =    131,072
    const size_t WS_NEEDED = 91881472;

    if (ws_size >= WS_NEEDED) {
        unsigned*       UT     = (unsigned*)((char*)d_ws + OFF_UT);
        unsigned*       xT     = (unsigned*)((char*)d_ws + OFF_XT);
        unsigned short* part   = (unsigned short*)((char*)d_ws + OFF_PART);
        unsigned short* specbf = (unsigned short*)((char*)d_ws + OFF_SPECB);

        dim3 gu(NPAD / 64, K_EIG / 64);   // 800 x 8
        prep_u<<<gu, 256, 0, stream>>>(U, UT);

        dim3 gx(NPAD / 64, F_DIM / 64);   // 800 x 2
        prep_x<<<gx, 256, 0, stream>>>(x, xT);

        dim3 g1(K_EIG / 64, NSPLITS);     // 8 x 200 = 1600 blocks
        k_spec<<<g1, 256, 0, stream>>>((const unsigned short*)UT,
                                       (const unsigned short*)xT, part);

        k_reduce<<<(K_EIG * F_DIM) / 256, 256, 0, stream>>>(part, g, specbf);

        int nb2 = (N_NODES + 63) / 64;    // 782
        k_out<<<nb2, 256, 0, stream>>>(U, specbf, out);
    } else {
        float* specT = (float*)d_ws;      // 256 KB
        hipMemsetAsync(specT, 0, (size_t)K_EIG * F_DIM * sizeof(float), stream);
        dim3 g1(K_EIG / 64, 64);
        k_spec_v1<<<g1, 256, 0, stream>>>(U, g, x, specT);
        int nb2 = (N_NODES + 127) / 128;
        k_out_v1<<<nb2, 256, 0, stream>>>(U, specT, out);
    }
}